// Round 7
// baseline (454.328 us; speedup 1.0000x reference)
//
#include <hip/hip_runtime.h>
#include <hip/hip_bf16.h>
#include <math.h>

#define NTOK 8192
#define HID  1024
#define ISZ  256
#define NEXP 16
#define NBIG 4096  // NEXP*ISZ

typedef __attribute__((ext_vector_type(8))) short bf16x8;
typedef __attribute__((ext_vector_type(4))) float f32x4;

#define MFMA16(a, b, c) __builtin_amdgcn_mfma_f32_16x16x32_bf16(a, b, c, 0, 0, 0)

__device__ __forceinline__ unsigned short f2bf(float f) {
  unsigned u = __float_as_uint(f);
  u += 0x7fff + ((u >> 16) & 1);
  return (unsigned short)(u >> 16);
}

__device__ __forceinline__ void async16(void* l, const void* g) {
  __builtin_amdgcn_global_load_lds(
      (const __attribute__((address_space(1))) unsigned int*)g,
      (__attribute__((address_space(3))) unsigned int*)l, 16, 0, 0);
}

// ---------------- sim_matrix column inverse norms ----------------
__global__ void simnorm_kernel(const float* __restrict__ sm, float* __restrict__ inv_smn) {
  __shared__ float red[16][17];
  int t = threadIdx.x;
  int e = t & 15, g = t >> 4;
  float ss = 0.f;
  for (int c = g; c < HID; c += 16) {
    float v = sm[c * NEXP + e];
    ss += v * v;
  }
  red[e][g] = ss;
  __syncthreads();
  if (t < 16) {
    float s = 0.f;
    #pragma unroll
    for (int i = 0; i < 16; i++) s += red[t][i];
    inv_smn[t] = 1.f / fmaxf(sqrtf(s), 1e-12f);
  }
}

// ---------------- gate: scores, k, routing weights, bf16 cast of x ----------------
__global__ __launch_bounds__(256)
void gate_kernel(const float* __restrict__ x, const float* __restrict__ sm,
                 const float* __restrict__ thr, const float* __restrict__ inv_smn,
                 float* __restrict__ scores_out, float* __restrict__ k_out,
                 float* __restrict__ rw_out, unsigned short* __restrict__ xb_out) {
  const int n = blockIdx.x;
  const int t = threadIdx.x;
  const int lane = t & 63, wave = t >> 6;
  const float* xr = x + (size_t)n * HID;

  float p[16];
  #pragma unroll
  for (int e = 0; e < 16; e++) p[e] = 0.f;
  float ss = 0.f;

  #pragma unroll
  for (int q = 0; q < 4; q++) {
    int c = t + q * 256;
    float v = xr[c];
    ss += v * v;
    xb_out[(size_t)n * HID + c] = f2bf(v);
    const float4* smr = (const float4*)(sm + (size_t)c * NEXP);
    float4 s0 = smr[0], s1 = smr[1], s2 = smr[2], s3 = smr[3];
    p[0] += v * s0.x;  p[1] += v * s0.y;  p[2] += v * s0.z;  p[3] += v * s0.w;
    p[4] += v * s1.x;  p[5] += v * s1.y;  p[6] += v * s1.z;  p[7] += v * s1.w;
    p[8] += v * s2.x;  p[9] += v * s2.y;  p[10] += v * s2.z; p[11] += v * s2.w;
    p[12] += v * s3.x; p[13] += v * s3.y; p[14] += v * s3.z; p[15] += v * s3.w;
  }

  #pragma unroll
  for (int off = 32; off > 0; off >>= 1) {
    ss += __shfl_down(ss, off, 64);
    #pragma unroll
    for (int e = 0; e < 16; e++) p[e] += __shfl_down(p[e], off, 64);
  }

  __shared__ float red[4][17];
  __shared__ float sc[16];
  if (lane == 0) {
    red[wave][0] = ss;
    #pragma unroll
    for (int e = 0; e < 16; e++) red[wave][1 + e] = p[e];
  }
  __syncthreads();

  if (t < 16) {
    float d = red[0][1 + t] + red[1][1 + t] + red[2][1 + t] + red[3][1 + t];
    float ssum = red[0][0] + red[1][0] + red[2][0] + red[3][0];
    float inv_x = 1.f / fmaxf(sqrtf(ssum), 1e-12f);
    float s = d * inv_x * inv_smn[t];
    scores_out[(size_t)n * 16 + t] = s;
    sc[t] = s;
  }
  __syncthreads();

  if (t < 16) {
    float thrv = thr[0];
    float s = sc[t];
    bool act = s > thrv;
    float m = act ? s : -INFINITY;
    int cnt = act ? 1 : 0;
    #pragma unroll
    for (int off = 8; off > 0; off >>= 1) {
      m = fmaxf(m, __shfl_xor(m, off, 16));
      cnt += __shfl_xor(cnt, off, 16);
    }
    float pv;
    if (cnt > 0) pv = act ? expf(s - m) : 0.f;
    else         pv = 1.f;
    float sum = pv;
    #pragma unroll
    for (int off = 8; off > 0; off >>= 1) sum += __shfl_xor(sum, off, 16);
    rw_out[(size_t)n * 16 + t] = pv / sum;
    if (t == 0) k_out[n] = (float)cnt;
  }
}

// ---------------- transpose + bf16 cast (per-expert 2D transpose) ----------------
__global__ __launch_bounds__(256)
void transpose_cast_kernel(const float* __restrict__ src, unsigned short* __restrict__ dst,
                           int R, int C, int dstride, int e_src_stride, int e_dst_mult) {
  __shared__ float tile[32][33];
  const int e = blockIdx.z;
  const int r0 = blockIdx.y * 32, c0 = blockIdx.x * 32;
  const int tx = threadIdx.x & 31, ty = threadIdx.x >> 5;
  const float* s = src + (size_t)e * e_src_stride;
  #pragma unroll
  for (int q = 0; q < 4; q++) {
    int r = r0 + ty + q * 8;
    tile[ty + q * 8][tx] = s[(size_t)r * C + c0 + tx];
  }
  __syncthreads();
  unsigned short* d = dst + (size_t)e * e_dst_mult;
  #pragma unroll
  for (int q = 0; q < 4; q++) {
    int cc = c0 + ty + q * 8;
    int r  = r0 + tx;
    d[(size_t)cc * dstride + r] = f2bf(tile[tx][ty + q * 8]);
  }
}

// ======= GEMM1: 256x256, BK=64, 8 waves, SINGLE-buffer, 2 blocks/CU =======
// m97-style: {stage 8 gload_lds; __syncthreads; 24 ds_read + 64 MFMA
// (compiler-scheduled, no pinning); __syncthreads}. Cross-block overlap hides
// the stage drain. LDS 64 KiB: A [256r][128B] @0, B [256r][128B] @32768.
// Swizzle byte^=(r&7)<<4 via pre-swizzled global source + same XOR on reads.
template <int KEXT, int LD, int NBN>
__global__ __launch_bounds__(512, 4)
void gemm1_k(const unsigned short* __restrict__ A, const unsigned short* __restrict__ B,
             unsigned short* __restrict__ Cb, const float* __restrict__ rw) {
  __shared__ __align__(1024) char lds[65536];
  constexpr int NT = KEXT / 64;
  const int tid = threadIdx.x;
  const int lane = tid & 63, wid = tid >> 6;
  const int wm = wid >> 2, wn = wid & 3;   // 2 x 4 waves, wave tile 128x64
  const int lr = lane & 15;

  const int nwg = gridDim.x, cpx = nwg >> 3;
  const int wg = (blockIdx.x & 7) * cpx + (blockIdx.x >> 3);
  const int bm = wg / NBN, bn = wg % NBN;

  const int swz = (lr & 7) << 4;
  const int colk0 = ((lane >> 4) * 16) ^ swz;
  const int colk1 = (64 + (lane >> 4) * 16) ^ swz;
  const int wmo = wm * 16384, wno = wn * 8192, lro = lr * 128;

  // staging decode: A/B tiles [256 r][128 B]; 4 units x 512 thr x 16 B each
  int sRow[4], sCol[4], so[4];
  #pragma unroll
  for (int i = 0; i < 4; i++) {
    int o = (i * 512 + tid) * 16;
    so[i] = o;
    int r = o >> 7, cb = o & 127;
    sRow[i] = r; sCol[i] = (cb ^ ((r & 7) << 4)) >> 1;
  }

  const unsigned short* Ag = A + (size_t)bm * 256 * LD;
  const unsigned short* Bg = B + (size_t)bn * 256 * LD;

  f32x4 acc[8][4];
  #pragma unroll
  for (int m = 0; m < 8; m++)
    #pragma unroll
    for (int n = 0; n < 4; n++) acc[m][n] = (f32x4){0.f, 0.f, 0.f, 0.f};

  #pragma unroll 1
  for (int t = 0; t < NT; ++t) {
    const int kt = t * 64;
    #pragma unroll
    for (int i = 0; i < 4; i++) {
      async16(lds + so[i],         Ag + (size_t)sRow[i] * LD + kt + sCol[i]);
      async16(lds + 32768 + so[i], Bg + (size_t)sRow[i] * LD + kt + sCol[i]);
    }
    __syncthreads();   // drains vmcnt (gload_lds) + barrier

    // kk = 0
    {
      bf16x8 a[8], b[4];
      #pragma unroll
      for (int mf = 0; mf < 8; mf++)
        a[mf] = *(const bf16x8*)(lds + wmo + mf * 2048 + lro + colk0);
      #pragma unroll
      for (int nf = 0; nf < 4; nf++)
        b[nf] = *(const bf16x8*)(lds + 32768 + wno + nf * 2048 + lro + colk0);
      #pragma unroll
      for (int mf = 0; mf < 8; mf++)
        #pragma unroll
        for (int nf = 0; nf < 4; nf++)
          acc[mf][nf] = MFMA16(a[mf], b[nf], acc[mf][nf]);
    }
    // kk = 1
    {
      bf16x8 a[8], b[4];
      #pragma unroll
      for (int mf = 0; mf < 8; mf++)
        a[mf] = *(const bf16x8*)(lds + wmo + mf * 2048 + lro + colk1);
      #pragma unroll
      for (int nf = 0; nf < 4; nf++)
        b[nf] = *(const bf16x8*)(lds + 32768 + wno + nf * 2048 + lro + colk1);
      #pragma unroll
      for (int mf = 0; mf < 8; mf++)
        #pragma unroll
        for (int nf = 0; nf < 4; nf++)
          acc[mf][nf] = MFMA16(a[mf], b[nf], acc[mf][nf]);
    }
    __syncthreads();   // write-after-read protection for next stage
  }

  // epilogue: C/D layout col=lane&15, row=(lane>>4)*4+j
  const int jr = (lane >> 4) * 4;
  float wrow[8][4];
  #pragma unroll
  for (int m = 0; m < 8; m++)
    #pragma unroll
    for (int j = 0; j < 4; j++)
      wrow[m][j] = rw[(size_t)(bm * 256 + wm * 128 + m * 16 + jr + j) * 16 + bn];
  #pragma unroll
  for (int m = 0; m < 8; m++) {
    #pragma unroll
    for (int n = 0; n < 4; n++) {
      int col = bn * 256 + wn * 64 + n * 16 + lr;
      #pragma unroll
      for (int j = 0; j < 4; j++) {
        int r = bm * 256 + wm * 128 + m * 16 + jr + j;
        float v = acc[m][n][j];
        float g = 0.7978845608f * (v + 0.044715f * v * v * v);
        float e = __expf(2.f * g);
        float th = 1.f - 2.f / (e + 1.f);   // tanh(g), inf-safe
        float ge = 0.5f * v * (1.f + th);
        Cb[(size_t)r * NBIG + col] = f2bf(ge * wrow[m][j]);
      }
    }
  }
}

// ======= GEMM2: 128x128, BK=64, 4 waves, SINGLE-buffer, 4 blocks/CU =======
// Same m97-style loop. LDS 32 KiB: A [128r][128B] @0, B @16384. Grid 512.
template <int K>
__global__ __launch_bounds__(256, 4)
void gemm2_k(const unsigned short* __restrict__ A, const unsigned short* __restrict__ B,
             float* __restrict__ Cf) {
  __shared__ __align__(1024) char lds[32768];
  constexpr int NT = K / 64;
  const int tid = threadIdx.x;
  const int lane = tid & 63, wid = tid >> 6;
  const int wm = wid >> 1, wn = wid & 1;   // 2 x 2 waves, wave tile 64x64
  const int lr = lane & 15;

  const int wg = (blockIdx.x & 7) * 64 + (blockIdx.x >> 3);  // nwg = 512
  const int bm = wg >> 3, bn = wg & 7;   // 64 M-tiles x 8 N-tiles

  const int swz = (lr & 7) << 4;
  const int colk0 = ((lane >> 4) * 16) ^ swz;
  const int colk1 = (64 + (lane >> 4) * 16) ^ swz;
  const int wmo = wm * 8192, wno = wn * 8192, lro = lr * 128;

  // staging decode: A/B tiles [128 r][128 B]; 4 units x 256 thr x 16 B each
  int sRow[4], sCol[4], so[4];
  #pragma unroll
  for (int i = 0; i < 4; i++) {
    int o = (i * 256 + tid) * 16;
    so[i] = o;
    int r = o >> 7, cb = o & 127;
    sRow[i] = r; sCol[i] = (cb ^ ((r & 7) << 4)) >> 1;
  }

  const unsigned short* Ag = A + (size_t)bm * 128 * K;
  const unsigned short* Bg = B + (size_t)bn * 128 * K;

  f32x4 acc[4][4];
  #pragma unroll
  for (int m = 0; m < 4; m++)
    #pragma unroll
    for (int n = 0; n < 4; n++) acc[m][n] = (f32x4){0.f, 0.f, 0.f, 0.f};

  #pragma unroll 1
  for (int t = 0; t < NT; ++t) {
    const int kt = t * 64;
    #pragma unroll
    for (int i = 0; i < 4; i++) {
      async16(lds + so[i],         Ag + (size_t)sRow[i] * K + kt + sCol[i]);
      async16(lds + 16384 + so[i], Bg + (size_t)sRow[i] * K + kt + sCol[i]);
    }
    __syncthreads();

    {
      bf16x8 a[4], b[4];
      #pragma unroll
      for (int mf = 0; mf < 4; mf++)
        a[mf] = *(const bf16x8*)(lds + wmo + mf * 2048 + lro + colk0);
      #pragma unroll
      for (int nf = 0; nf < 4; nf++)
        b[nf] = *(const bf16x8*)(lds + 16384 + wno + nf * 2048 + lro + colk0);
      #pragma unroll
      for (int mf = 0; mf < 4; mf++)
        #pragma unroll
        for (int nf = 0; nf < 4; nf++)
          acc[mf][nf] = MFMA16(a[mf], b[nf], acc[mf][nf]);
    }
    {
      bf16x8 a[4], b[4];
      #pragma unroll
      for (int mf = 0; mf < 4; mf++)
        a[mf] = *(const bf16x8*)(lds + wmo + mf * 2048 + lro + colk1);
      #pragma unroll
      for (int nf = 0; nf < 4; nf++)
        b[nf] = *(const bf16x8*)(lds + 16384 + wno + nf * 2048 + lro + colk1);
      #pragma unroll
      for (int mf = 0; mf < 4; mf++)
        #pragma unroll
        for (int nf = 0; nf < 4; nf++)
          acc[mf][nf] = MFMA16(a[mf], b[nf], acc[mf][nf]);
    }
    __syncthreads();
  }

  // epilogue: f32 store
  const int jr = (lane >> 4) * 4;
  #pragma unroll
  for (int m = 0; m < 4; m++) {
    #pragma unroll
    for (int n = 0; n < 4; n++) {
      int col = bn * 128 + wn * 64 + n * 16 + lr;
      #pragma unroll
      for (int j = 0; j < 4; j++) {
        int r = bm * 128 + wm * 64 + m * 16 + jr + j;
        Cf[(size_t)r * HID + col] = acc[m][n][j];
      }
    }
  }
}

extern "C" void kernel_launch(void* const* d_in, const int* in_sizes, int n_in,
                              void* d_out, int out_size, void* d_ws, size_t ws_size,
                              hipStream_t stream) {
  const float* x   = (const float*)d_in[0];
  const float* sm  = (const float*)d_in[1];
  const float* thr = (const float*)d_in[2];
  const float* w1  = (const float*)d_in[3];
  const float* w2  = (const float*)d_in[4];

  float* out_final  = (float*)d_out;
  float* out_scores = out_final + (size_t)NTOK * HID;
  float* out_k      = out_scores + (size_t)NTOK * NEXP;

  char* ws = (char*)d_ws;
  size_t off = 0;
  float* inv_smn = (float*)(ws + off); off += 256;
  float* rwbuf   = (float*)(ws + off); off += (size_t)NTOK * NEXP * 4;
  unsigned short* Xb  = (unsigned short*)(ws + off); off += (size_t)NTOK * HID * 2;
  unsigned short* W1T = (unsigned short*)(ws + off); off += (size_t)NBIG * HID * 2;
  unsigned short* W2T = (unsigned short*)(ws + off); off += (size_t)HID * NBIG * 2;
  unsigned short* H   = (unsigned short*)(ws + off); off += (size_t)NTOK * NBIG * 2;

  simnorm_kernel<<<1, 256, 0, stream>>>(sm, inv_smn);
  gate_kernel<<<NTOK, 256, 0, stream>>>(x, sm, thr, inv_smn, out_scores, out_k, rwbuf, Xb);
  transpose_cast_kernel<<<dim3(ISZ / 32, HID / 32, NEXP), 256, 0, stream>>>(
      w1, W1T, HID, ISZ, HID, HID * ISZ, ISZ * HID);
  transpose_cast_kernel<<<dim3(HID / 32, ISZ / 32, NEXP), 256, 0, stream>>>(
      w2, W2T, ISZ, HID, NBIG, ISZ * HID, ISZ);

  // H = gelu(Xb @ W1T^T) * rw   [8192 x 4096], 512 blocks, 2/CU
  gemm1_k<HID, HID, 16><<<512, 512, 0, stream>>>(Xb, W1T, H, rwbuf);
  // final = H @ W2T^T            [8192 x 1024], 512 blocks (128x128), 4/CU
  gemm2_k<NBIG><<<512, 256, 0, stream>>>(H, W2T, out_final);
}

// Round 8
// 235.766 us; speedup vs baseline: 1.9270x; 1.9270x over previous
//
#include <hip/hip_runtime.h>
#include <hip/hip_bf16.h>
#include <math.h>

#define NTOK 8192
#define HID  1024
#define ISZ  256
#define NEXP 16
#define NBIG 4096  // NEXP*ISZ

typedef __attribute__((ext_vector_type(8))) short bf16x8;
typedef __attribute__((ext_vector_type(4))) float f32x4;

#define MFMA16(a, b, c) __builtin_amdgcn_mfma_f32_16x16x32_bf16(a, b, c, 0, 0, 0)

__device__ __forceinline__ unsigned short f2bf(float f) {
  unsigned u = __float_as_uint(f);
  u += 0x7fff + ((u >> 16) & 1);
  return (unsigned short)(u >> 16);
}

__device__ __forceinline__ void async16(void* l, const void* g) {
  __builtin_amdgcn_global_load_lds(
      (const __attribute__((address_space(1))) unsigned int*)g,
      (__attribute__((address_space(3))) unsigned int*)l, 16, 0, 0);
}

// ---------------- sim_matrix column inverse norms ----------------
__global__ void simnorm_kernel(const float* __restrict__ sm, float* __restrict__ inv_smn) {
  __shared__ float red[16][17];
  int t = threadIdx.x;
  int e = t & 15, g = t >> 4;
  float ss = 0.f;
  for (int c = g; c < HID; c += 16) {
    float v = sm[c * NEXP + e];
    ss += v * v;
  }
  red[e][g] = ss;
  __syncthreads();
  if (t < 16) {
    float s = 0.f;
    #pragma unroll
    for (int i = 0; i < 16; i++) s += red[t][i];
    inv_smn[t] = 1.f / fmaxf(sqrtf(s), 1e-12f);
  }
}

// ---------------- gate: scores, k, routing weights, bf16 cast of x ----------------
__global__ __launch_bounds__(256)
void gate_kernel(const float* __restrict__ x, const float* __restrict__ sm,
                 const float* __restrict__ thr, const float* __restrict__ inv_smn,
                 float* __restrict__ scores_out, float* __restrict__ k_out,
                 float* __restrict__ rw_out, unsigned short* __restrict__ xb_out) {
  const int n = blockIdx.x;
  const int t = threadIdx.x;
  const int lane = t & 63, wave = t >> 6;
  const float* xr = x + (size_t)n * HID;

  float p[16];
  #pragma unroll
  for (int e = 0; e < 16; e++) p[e] = 0.f;
  float ss = 0.f;

  #pragma unroll
  for (int q = 0; q < 4; q++) {
    int c = t + q * 256;
    float v = xr[c];
    ss += v * v;
    xb_out[(size_t)n * HID + c] = f2bf(v);
    const float4* smr = (const float4*)(sm + (size_t)c * NEXP);
    float4 s0 = smr[0], s1 = smr[1], s2 = smr[2], s3 = smr[3];
    p[0] += v * s0.x;  p[1] += v * s0.y;  p[2] += v * s0.z;  p[3] += v * s0.w;
    p[4] += v * s1.x;  p[5] += v * s1.y;  p[6] += v * s1.z;  p[7] += v * s1.w;
    p[8] += v * s2.x;  p[9] += v * s2.y;  p[10] += v * s2.z; p[11] += v * s2.w;
    p[12] += v * s3.x; p[13] += v * s3.y; p[14] += v * s3.z; p[15] += v * s3.w;
  }

  #pragma unroll
  for (int off = 32; off > 0; off >>= 1) {
    ss += __shfl_down(ss, off, 64);
    #pragma unroll
    for (int e = 0; e < 16; e++) p[e] += __shfl_down(p[e], off, 64);
  }

  __shared__ float red[4][17];
  __shared__ float sc[16];
  if (lane == 0) {
    red[wave][0] = ss;
    #pragma unroll
    for (int e = 0; e < 16; e++) red[wave][1 + e] = p[e];
  }
  __syncthreads();

  if (t < 16) {
    float d = red[0][1 + t] + red[1][1 + t] + red[2][1 + t] + red[3][1 + t];
    float ssum = red[0][0] + red[1][0] + red[2][0] + red[3][0];
    float inv_x = 1.f / fmaxf(sqrtf(ssum), 1e-12f);
    float s = d * inv_x * inv_smn[t];
    scores_out[(size_t)n * 16 + t] = s;
    sc[t] = s;
  }
  __syncthreads();

  if (t < 16) {
    float thrv = thr[0];
    float s = sc[t];
    bool act = s > thrv;
    float m = act ? s : -INFINITY;
    int cnt = act ? 1 : 0;
    #pragma unroll
    for (int off = 8; off > 0; off >>= 1) {
      m = fmaxf(m, __shfl_xor(m, off, 16));
      cnt += __shfl_xor(cnt, off, 16);
    }
    float pv;
    if (cnt > 0) pv = act ? expf(s - m) : 0.f;
    else         pv = 1.f;
    float sum = pv;
    #pragma unroll
    for (int off = 8; off > 0; off >>= 1) sum += __shfl_xor(sum, off, 16);
    rw_out[(size_t)n * 16 + t] = pv / sum;
    if (t == 0) k_out[n] = (float)cnt;
  }
}

// ---------------- transpose + bf16 cast (per-expert 2D transpose) ----------------
__global__ __launch_bounds__(256)
void transpose_cast_kernel(const float* __restrict__ src, unsigned short* __restrict__ dst,
                           int R, int C, int dstride, int e_src_stride, int e_dst_mult) {
  __shared__ float tile[32][33];
  const int e = blockIdx.z;
  const int r0 = blockIdx.y * 32, c0 = blockIdx.x * 32;
  const int tx = threadIdx.x & 31, ty = threadIdx.x >> 5;
  const float* s = src + (size_t)e * e_src_stride;
  #pragma unroll
  for (int q = 0; q < 4; q++) {
    int r = r0 + ty + q * 8;
    tile[ty + q * 8][tx] = s[(size_t)r * C + c0 + tx];
  }
  __syncthreads();
  unsigned short* d = dst + (size_t)e * e_dst_mult;
  #pragma unroll
  for (int q = 0; q < 4; q++) {
    int cc = c0 + ty + q * 8;
    int r  = r0 + tx;
    d[(size_t)cc * dstride + r] = f2bf(tile[tx][ty + q * 8]);
  }
}

// ================= 256x256 8-wave dbuf MFMA GEMM, minimal-sync =================
// Per K-tile: {8 gloads (tile t+1 -> other buf); 24 ds_read + 64 MFMA written
// plainly (compiler does fine-grained lgkmcnt interleave); SBAR; vmcnt(0);
// s_barrier; SBAR}. One barrier + one wait per K-tile; no lgkm asm; no setprio.
// Race ledger: RAW (staged data ready) via tile-end vmcnt(0)+barrier; WAR
// (DMA overwrite vs reads) via reads-complete-before-end-barrier + stagings
// issued after it; sched_barrier(0) on both sides of the boundary stops
// compiler hoist/sink across it (r3 lesson).
#define GTILE(CA, CB, NA, NB, kn)                                                     \
  {                                                                                   \
    _Pragma("unroll")                                                                 \
    for (int i = 0; i < 2; i++) {                                                     \
      async16((NA) + o16[i],         Ag + (size_t)aRow[i] * LD + (kn) + aCol[i]);     \
      async16((NB) + o16[i],         Bg + (size_t)bRow[i] * LD + (kn) + bCol[i]);     \
      async16((NA) + 16384 + o16[i], Ag + (size_t)(aRow[i] + 64) * LD + (kn) + aCol[i]); \
      async16((NB) + 16384 + o16[i], Bg + (size_t)(bRow[i] + 32) * LD + (kn) + bCol[i]); \
    }                                                                                 \
    _Pragma("unroll")                                                                 \
    for (int kk = 0; kk < 2; kk++) {                                                  \
      const int ck = kk ? colk1 : colk0;                                              \
      bf16x8 a[8], b[4];                                                              \
      _Pragma("unroll")                                                               \
      for (int q = 0; q < 2; q++)                                                     \
        _Pragma("unroll")                                                             \
        for (int ml = 0; ml < 4; ml++)                                                \
          a[q * 4 + ml] = *(const bf16x8*)((CA) + q * 16384 + wmo + ml * 2048 + lro + ck); \
      _Pragma("unroll")                                                               \
      for (int qn = 0; qn < 2; qn++)                                                  \
        _Pragma("unroll")                                                             \
        for (int nl = 0; nl < 2; nl++)                                                \
          b[qn * 2 + nl] = *(const bf16x8*)((CB) + qn * 16384 + wno + nl * 2048 + lro + ck); \
      _Pragma("unroll")                                                               \
      for (int m8 = 0; m8 < 8; m8++)                                                  \
        _Pragma("unroll")                                                             \
        for (int n4 = 0; n4 < 4; n4++)                                                \
          acc[m8][n4] = MFMA16(a[m8], b[n4], acc[m8][n4]);                            \
    }                                                                                 \
    __builtin_amdgcn_sched_barrier(0);                                                \
    asm volatile("s_waitcnt vmcnt(0)" ::: "memory");                                  \
    __builtin_amdgcn_s_barrier();                                                     \
    __builtin_amdgcn_sched_barrier(0);                                                \
  }

// EPI: 1 = gelu*rw -> bf16 Cb;  2 = f32 -> selected Cf
template <int EPI, int KEXT, int LD, int NBN, int SPLITK>
__global__ __launch_bounds__(512, 2)
void gemm256(const unsigned short* __restrict__ A, const unsigned short* __restrict__ B,
             float* __restrict__ Cf, float* __restrict__ Cf2,
             unsigned short* __restrict__ Cb, const float* __restrict__ rw) {
  __shared__ __align__(1024) char lds[131072];
  constexpr int NT = KEXT / 64;
  const int tid = threadIdx.x;
  const int lane = tid & 63, wid = tid >> 6;
  const int wm = wid >> 2, wn = wid & 3;
  const int lr = lane & 15;

  // bijective XCD swizzle (gridDim.x % 8 == 0 for all instantiations)
  const int nwg = gridDim.x;
  const int cpx = nwg >> 3;
  int wg = (blockIdx.x & 7) * cpx + (blockIdx.x >> 3);
  int kz = 0;
  if (SPLITK == 2) { kz = wg / (nwg >> 1); wg = wg % (nwg >> 1); }
  const int bm = wg / NBN, bn = wg % NBN;

  const int swz = (lr & 7) << 4;
  const int colk0 = ((lane >> 4) * 16) ^ swz;
  const int colk1 = (64 + (lane >> 4) * 16) ^ swz;
  const int wmo = wm * 8192, wno = wn * 4096, lro = lr * 128;

  int aRow[2], aCol[2], bRow[2], bCol[2], o16[2];
  #pragma unroll
  for (int i = 0; i < 2; i++) {
    int o = (i * 512 + tid) * 16;
    o16[i] = o;
    { int wmb = o >> 13, ob = o & 8191, r = ob >> 7, cb = ob & 127;
      aRow[i] = wmb * 128 + r; aCol[i] = (cb ^ ((r & 7) << 4)) >> 1; }
    { int wnb = o >> 12, ob = o & 4095, r = ob >> 7, cb = ob & 127;
      bRow[i] = wnb * 64 + r; bCol[i] = (cb ^ ((r & 7) << 4)) >> 1; }
  }

  const unsigned short* Ag = A + (size_t)bm * 256 * LD + (size_t)kz * KEXT;
  const unsigned short* Bg = B + (size_t)bn * 256 * LD + (size_t)kz * KEXT;

  f32x4 acc[8][4];
  #pragma unroll
  for (int m = 0; m < 8; m++)
    #pragma unroll
    for (int n = 0; n < 4; n++) acc[m][n] = (f32x4){0.f, 0.f, 0.f, 0.f};

  // prologue: stage tile 0 into buf0, drain, barrier
  #pragma unroll
  for (int i = 0; i < 2; i++) {
    async16(lds + o16[i],                 Ag + (size_t)aRow[i] * LD + aCol[i]);
    async16(lds + 65536 + o16[i],         Bg + (size_t)bRow[i] * LD + bCol[i]);
    async16(lds + 16384 + o16[i],         Ag + (size_t)(aRow[i] + 64) * LD + aCol[i]);
    async16(lds + 65536 + 16384 + o16[i], Bg + (size_t)(bRow[i] + 32) * LD + bCol[i]);
  }
  asm volatile("s_waitcnt vmcnt(0)" ::: "memory");
  __builtin_amdgcn_s_barrier();
  __builtin_amdgcn_sched_barrier(0);

  #pragma unroll 1
  for (int t = 0; t < NT; t += 2) {
    // tile t: read buf0, stage t+1 -> buf1
    GTILE(lds,         lds + 65536,         lds + 32768, lds + 65536 + 32768,
          ((t + 1) & (NT - 1)) << 6)
    // tile t+1: read buf1, stage t+2 -> buf0
    GTILE(lds + 32768, lds + 65536 + 32768, lds,         lds + 65536,
          ((t + 2) & (NT - 1)) << 6)
  }

  asm volatile("s_waitcnt vmcnt(0)" ::: "memory");

  // epilogue: C/D layout col=lane&15, row=(lane>>4)*4+j
  const int jr = (lane >> 4) * 4;
  if (EPI == 1) {
    float wrow[8][4];
    #pragma unroll
    for (int m = 0; m < 8; m++)
      #pragma unroll
      for (int j = 0; j < 4; j++)
        wrow[m][j] = rw[(size_t)(bm * 256 + wm * 128 + m * 16 + jr + j) * 16 + bn];
    #pragma unroll
    for (int m = 0; m < 8; m++) {
      #pragma unroll
      for (int n = 0; n < 4; n++) {
        int col = bn * 256 + wn * 64 + n * 16 + lr;
        #pragma unroll
        for (int j = 0; j < 4; j++) {
          int r = bm * 256 + wm * 128 + m * 16 + jr + j;
          float v = acc[m][n][j];
          float g = 0.7978845608f * (v + 0.044715f * v * v * v);
          float e = __expf(2.f * g);
          float th = 1.f - 2.f / (e + 1.f);   // tanh(g), inf-safe
          float ge = 0.5f * v * (1.f + th);
          Cb[(size_t)r * NBIG + col] = f2bf(ge * wrow[m][j]);
        }
      }
    }
  } else {
    float* cfp = (SPLITK == 2 && kz == 1) ? Cf2 : Cf;
    #pragma unroll
    for (int m = 0; m < 8; m++) {
      #pragma unroll
      for (int n = 0; n < 4; n++) {
        int col = bn * 256 + wn * 64 + n * 16 + lr;
        #pragma unroll
        for (int j = 0; j < 4; j++) {
          int r = bm * 256 + wm * 128 + m * 16 + jr + j;
          cfp[(size_t)r * HID + col] = acc[m][n][j];
        }
      }
    }
  }
}

// ---------------- out += p1 (f32x4, grid-stride) ----------------
__global__ __launch_bounds__(256)
void addk(float* __restrict__ out, const float* __restrict__ p1, int n4) {
  int i = blockIdx.x * blockDim.x + threadIdx.x;
  const int stride = gridDim.x * blockDim.x;
  for (; i < n4; i += stride) {
    float4 a = ((const float4*)out)[i];
    float4 b = ((const float4*)p1)[i];
    a.x += b.x; a.y += b.y; a.z += b.z; a.w += b.w;
    ((float4*)out)[i] = a;
  }
}

extern "C" void kernel_launch(void* const* d_in, const int* in_sizes, int n_in,
                              void* d_out, int out_size, void* d_ws, size_t ws_size,
                              hipStream_t stream) {
  const float* x   = (const float*)d_in[0];
  const float* sm  = (const float*)d_in[1];
  const float* thr = (const float*)d_in[2];
  const float* w1  = (const float*)d_in[3];
  const float* w2  = (const float*)d_in[4];

  float* out_final  = (float*)d_out;
  float* out_scores = out_final + (size_t)NTOK * HID;
  float* out_k      = out_scores + (size_t)NTOK * NEXP;

  char* ws = (char*)d_ws;
  size_t off = 0;
  float* inv_smn = (float*)(ws + off); off += 256;
  float* rwbuf   = (float*)(ws + off); off += (size_t)NTOK * NEXP * 4;
  unsigned short* Xb  = (unsigned short*)(ws + off); off += (size_t)NTOK * HID * 2;
  unsigned short* W1T = (unsigned short*)(ws + off); off += (size_t)NBIG * HID * 2;
  unsigned short* W2T = (unsigned short*)(ws + off); off += (size_t)HID * NBIG * 2;
  unsigned short* H   = (unsigned short*)(ws + off); off += (size_t)NTOK * NBIG * 2;
  float* P1 = (float*)(ws + off);
  const bool split = ws_size >= off + (size_t)NTOK * HID * 4;

  simnorm_kernel<<<1, 256, 0, stream>>>(sm, inv_smn);
  gate_kernel<<<NTOK, 256, 0, stream>>>(x, sm, thr, inv_smn, out_scores, out_k, rwbuf, Xb);
  transpose_cast_kernel<<<dim3(ISZ / 32, HID / 32, NEXP), 256, 0, stream>>>(
      w1, W1T, HID, ISZ, HID, HID * ISZ, ISZ * HID);
  transpose_cast_kernel<<<dim3(HID / 32, ISZ / 32, NEXP), 256, 0, stream>>>(
      w2, W2T, ISZ, HID, NBIG, ISZ * HID, ISZ);

  // H = gelu(Xb @ W1T^T) * rw   [8192 x 4096], 512 blocks
  gemm256<1, HID, HID, 16, 1><<<512, 512, 0, stream>>>(Xb, W1T, nullptr, nullptr, H, rwbuf);

  if (split) {
    // final = H @ W2T^T via split-K=2: 256 blocks (full machine), then add
    gemm256<2, NBIG / 2, NBIG, 4, 2><<<256, 512, 0, stream>>>(H, W2T, out_final, P1, nullptr, nullptr);
    addk<<<2048, 256, 0, stream>>>(out_final, P1, NTOK * HID / 4);
  } else {
    // fallback: verified single-pass, 128 blocks
    gemm256<2, NBIG, NBIG, 4, 1><<<128, 512, 0, stream>>>(H, W2T, out_final, nullptr, nullptr, nullptr);
  }
}